// Round 15
// baseline (98.378 us; speedup 1.0000x reference)
//
#include <hip/hip_runtime.h>

#define N_NODES 50000
#define N_EDGES 800000
#define D_FEAT  128
#define EPS     1e-12f
#define CAP     64                                      // bucket slots/node

#define EDGE_BLOCKS (N_EDGES / 256)                     // 3125 (exact)
#define NORM_BLOCKS (N_NODES / 8)                       // 6250 (exact)

__device__ __forceinline__ unsigned int f2bf(float x) {
    unsigned int u = __float_as_uint(x);
    return (u + 0x7FFFu + ((u >> 16) & 1u)) >> 16;      // RNE
}
__device__ __forceinline__ float bf_lo(unsigned int w) {
    return __uint_as_float(w << 16);
}
__device__ __forceinline__ float bf_hi(unsigned int w) {
    return __uint_as_float(w & 0xFFFF0000u);
}
// D = a.bf16[0]*b.bf16[0] + a.bf16[1]*b.bf16[1] + c   (f32 products/accum)
__device__ __forceinline__ float dot2_bf16(unsigned int a, unsigned int b,
                                           float c) {
    float d;
    asm("v_dot2_f32_bf16 %0, %1, %2, %3"
        : "=v"(d) : "v"(a), "v"(b), "v"(c));
    return d;
}

// ---------------------------------------------------------------------------
// K0: zero counts (50000 ints = 12500 int4). 49 blocks, ~2 us.
// ---------------------------------------------------------------------------
__global__ void zero_counts_kernel(int* __restrict__ counts) {
    const int i = blockIdx.x * blockDim.x + threadIdx.x;
    if (i < N_NODES / 4)
        reinterpret_cast<int4*>(counts)[i] = make_int4(0, 0, 0, 0);
}

// ---------------------------------------------------------------------------
// K1: block-split co-kernel (independent halves run concurrently):
//   blocks [0, EDGE_BLOCKS)   : bucket scatter — ONE atomic pass builds the
//                               grouped edge lists directly
//   blocks [EDGE_BLOCKS, +N)  : per-node inv_norm + packed bf16 transcode
// ---------------------------------------------------------------------------
__global__ void bucket_norm_kernel(const int* __restrict__ src,
                                   const int* __restrict__ dst,
                                   int* __restrict__ counts,
                                   unsigned short* __restrict__ bucket,
                                   const float* __restrict__ feat,
                                   float* __restrict__ inv_norm,
                                   unsigned int* __restrict__ feat_bf) {
    const int b = blockIdx.x;
    if (b < EDGE_BLOCKS) {
        const int e = b * 256 + threadIdx.x;      // 3125*256 == N_EDGES exact
        const int d = dst[e];
        const int slot = atomicAdd(&counts[d], 1);
        if (slot < CAP)                            // never triggers (maxdeg~45)
            bucket[d * CAP + slot] = (unsigned short)src[e];
        return;
    }
    // norm half: half-wave (32 lanes) per node, float4 loads, uint2 stores
    const int nb  = b - EDGE_BLOCKS;
    const int g   = threadIdx.x >> 5;             // 0..7 group in block
    const int sub = threadIdx.x & 31;             // lane in group
    const int node = nb * 8 + g;                  // 6250*8 == N_NODES exact
    float4 v = reinterpret_cast<const float4*>(feat + (size_t)node * D_FEAT)[sub];
    unsigned int w0 = (f2bf(v.y) << 16) | f2bf(v.x);
    unsigned int w1 = (f2bf(v.w) << 16) | f2bf(v.z);
    *reinterpret_cast<uint2*>(feat_bf + (size_t)node * 64 + sub * 2) =
        make_uint2(w0, w1);
    float s = v.x * v.x + v.y * v.y + v.z * v.z + v.w * v.w;
    #pragma unroll
    for (int off = 16; off > 0; off >>= 1)        // stays within 32-lane group
        s += __shfl_xor(s, off, 64);
    if (sub == 0) {
        inv_norm[node] = 1.0f / fmaxf(sqrtf(s), EPS);
    }
}

// ---------------------------------------------------------------------------
// K2: fused per-node weight + aggregation over bf16 rows.
// One wave per node; deg <= CAP=64 -> one coalesced u16 id preload + shfl
// broadcast; 4 edges/iter via 16-lane groups; depth-2 pipeline.
// Dot product via raw-word v_dot2_f32_bf16 (both rows UNSCALED); all scales
// (beta, inv_norm[dst], inv_norm[src]) folded into the exp argument.
// ---------------------------------------------------------------------------
__global__ void fused_agg(const unsigned int* __restrict__ feat_bf,
                          const float* __restrict__ inv_norm,
                          const int* __restrict__ counts,
                          const unsigned short* __restrict__ bucket,
                          const float* __restrict__ beta,
                          float* __restrict__ out) {
    const int lane = threadIdx.x & 63;
    const int grp  = lane >> 4;       // 0..3  : edge slot
    const int sub  = lane & 15;       // lane within group
    const int node = blockIdx.x * (blockDim.x >> 6) + (threadIdx.x >> 6);
    if (node >= N_NODES) return;

    const int cnt = min(counts[node], CAP);
    float4* orow = reinterpret_cast<float4*>(out + (size_t)node * D_FEAT);
    if (cnt == 0) {                   // degree-0: zero row (ref semantics)
        if (grp == 0) {
            orow[2 * sub] = make_float4(0.f, 0.f, 0.f, 0.f);
            orow[2 * sub + 1] = make_float4(0.f, 0.f, 0.f, 0.f);
        }
        return;
    }

    // dst row RAW (unscaled) — scales are applied in the exp argument
    uint4 qd = reinterpret_cast<const uint4*>(feat_bf + (size_t)node * 64)[sub];
    const float bscale = inv_norm[node] * beta[0];

    float acc[8] = {0, 0, 0, 0, 0, 0, 0, 0};
    float denom = 0.0f;

    // coalesced preload of the node's id list (128 B per wave)
    const int myid = (int)bucket[node * CAP + min(lane, cnt - 1)];

    // stage 0 (edges 0..3)
    const int s0 = __shfl(myid, min(grp, cnt - 1), 64);
    uint4 q0 = reinterpret_cast<const uint4*>(feat_bf + (size_t)s0 * 64)[sub];
    float in0 = inv_norm[s0];

    // stage 1 (edges 4..7)
    uint4 q1 = make_uint4(0u, 0u, 0u, 0u);
    float in1 = 0.0f;
    if (4 < cnt) {
        const int s1 = __shfl(myid, min(4 + grp, cnt - 1), 64);
        q1 = reinterpret_cast<const uint4*>(feat_bf + (size_t)s1 * 64)[sub];
        in1 = inv_norm[s1];
    }

    for (int k0 = 0; k0 < cnt; k0 += 4) {
        // prefetch edges k0+8..k0+11 (2 stages ahead)
        uint4 q2 = make_uint4(0u, 0u, 0u, 0u);
        float in2 = 0.0f;
        if (k0 + 8 < cnt) {                       // wave-uniform branch
            const int s2 = __shfl(myid, min(k0 + 8 + grp, cnt - 1), 64);
            q2 = reinterpret_cast<const uint4*>(feat_bf + (size_t)s2 * 64)[sub];
            in2 = inv_norm[s2];
        }

        // raw bf16 dot via packed dot2 (no unpack, no prescale)
        float dot = dot2_bf16(q0.x, qd.x, 0.0f);
        dot = dot2_bf16(q0.y, qd.y, dot);
        dot = dot2_bf16(q0.z, qd.z, dot);
        dot = dot2_bf16(q0.w, qd.w, dot);
        #pragma unroll
        for (int off = 8; off > 0; off >>= 1)
            dot += __shfl_xor(dot, off, 64);

        const bool valid = (k0 + grp) < cnt;
        const float ee = valid ? __expf(dot * (bscale * in0)) : 0.0f;

        // unpack a only for the accumulate
        float a[8];
        a[0] = bf_lo(q0.x); a[1] = bf_hi(q0.x);
        a[2] = bf_lo(q0.y); a[3] = bf_hi(q0.y);
        a[4] = bf_lo(q0.z); a[5] = bf_hi(q0.z);
        a[6] = bf_lo(q0.w); a[7] = bf_hi(q0.w);
        #pragma unroll
        for (int j = 0; j < 8; ++j) acc[j] += ee * a[j];
        denom += ee;

        q0 = q1; in0 = in1;
        q1 = q2; in1 = in2;
    }

    #pragma unroll
    for (int j = 0; j < 8; ++j) {
        acc[j] += __shfl_xor(acc[j], 16, 64);
        acc[j] += __shfl_xor(acc[j], 32, 64);
    }
    denom += __shfl_xor(denom, 16, 64);
    denom += __shfl_xor(denom, 32, 64);

    if (grp == 0) {
        const float scale = 1.0f / denom;
        orow[2 * sub] = make_float4(acc[0] * scale, acc[1] * scale,
                                    acc[2] * scale, acc[3] * scale);
        orow[2 * sub + 1] = make_float4(acc[4] * scale, acc[5] * scale,
                                        acc[6] * scale, acc[7] * scale);
    }
}

extern "C" void kernel_launch(void* const* d_in, const int* in_sizes, int n_in,
                              void* d_out, int out_size, void* d_ws, size_t ws_size,
                              hipStream_t stream) {
    const float* feat = (const float*)d_in[0];
    const float* beta = (const float*)d_in[1];
    const int*   src  = (const int*)d_in[2];
    const int*   dst  = (const int*)d_in[3];
    float* out = (float*)d_out;

    // ws layout: inv_norm[N] f32 | counts[N] i32 | bucket[N*CAP] u16 |
    //            feat_bf[N*64] u32   (total ~19.6 MB)
    float*          inv_norm = (float*)d_ws;
    int*            counts   = (int*)(inv_norm + N_NODES);
    unsigned short* bucket   = (unsigned short*)(counts + N_NODES);
    unsigned int*   feat_bf  = (unsigned int*)(bucket + (size_t)N_NODES * CAP);

    zero_counts_kernel<<<49, 256, 0, stream>>>(counts);
    bucket_norm_kernel<<<EDGE_BLOCKS + NORM_BLOCKS, 256, 0, stream>>>(
        src, dst, counts, bucket, feat, inv_norm, feat_bf);
    {
        const int WPB = 4;
        int blocks = (N_NODES + WPB - 1) / WPB;
        fused_agg<<<blocks, WPB * 64, 0, stream>>>(feat_bf, inv_norm, counts,
                                                   bucket, beta, out);
    }
}

// Round 16
// 80.999 us; speedup vs baseline: 1.2146x; 1.2146x over previous
//
#include <hip/hip_runtime.h>

#define N_NODES 50000
#define N_EDGES 800000
#define D_FEAT  128
#define EPS     1e-12f
#define CAP     64                                      // bucket slots/node

#define NR          125                                 // node ranges
#define RANGE_NODES 400                                 // 50000/125 exact
#define RANGE_CAP   8192                                // mean 6400, +22σ
#define A_BLOCKS    ((N_EDGES + 1023) / 1024)           // 782
#define ANORM_BLOCKS ((N_NODES + 31) / 32)              // 1563 (32 nodes/blk)

__device__ __forceinline__ unsigned int f2bf(float x) {
    unsigned int u = __float_as_uint(x);
    return (u + 0x7FFFu + ((u >> 16) & 1u)) >> 16;      // RNE
}
__device__ __forceinline__ float bf_lo(unsigned int w) {
    return __uint_as_float(w << 16);
}
__device__ __forceinline__ float bf_hi(unsigned int w) {
    return __uint_as_float(w & 0xFFFF0000u);
}
// D = a.bf16[0]*b.bf16[0] + a.bf16[1]*b.bf16[1] + c   (f32 products/accum)
__device__ __forceinline__ float dot2_bf16(unsigned int a, unsigned int b,
                                           float c) {
    float d;
    asm("v_dot2_f32_bf16 %0, %1, %2, %3"
        : "=v"(d) : "v"(a), "v"(b), "v"(c));
    return d;
}

// ---------------------------------------------------------------------------
// K0: zero the 125 range cursors.
// ---------------------------------------------------------------------------
__global__ void zero_cursor_kernel(int* __restrict__ cursor) {
    if (threadIdx.x < NR) cursor[threadIdx.x] = 0;
}

// ---------------------------------------------------------------------------
// K1 (pass A + norm co-kernel):
//  blocks [0, A_BLOCKS): partition 1024 edges into NR ranges.
//    LDS histogram (LDS atomics give in-block rank) -> 1 global atomic per
//    (block,range) reserves space -> scatter packed (dstLocal:9|src:16).
//    97.7K global atomics instead of 800K.
//  blocks [A_BLOCKS, +ANORM_BLOCKS): inv_norm + bf16 transcode (32 nodes/blk).
// ---------------------------------------------------------------------------
__global__ __launch_bounds__(1024) void partition_norm_kernel(
        const int* __restrict__ src,
        const int* __restrict__ dst,
        int* __restrict__ cursor,
        unsigned int* __restrict__ area,          // [NR * RANGE_CAP]
        const float* __restrict__ feat,
        float* __restrict__ inv_norm,
        unsigned int* __restrict__ feat_bf) {
    __shared__ int hist[NR];
    __shared__ int base[NR];
    const int b = blockIdx.x;
    if (b < A_BLOCKS) {
        const int t = threadIdx.x;
        for (int i = t; i < NR; i += 1024) hist[i] = 0;
        __syncthreads();
        const int e = b * 1024 + t;
        int r = 0, lrank = 0;
        unsigned int w = 0;
        if (e < N_EDGES) {
            const int d = dst[e];
            r = d / RANGE_NODES;                  // magic-mul division
            const int dl = d - r * RANGE_NODES;
            w = ((unsigned int)dl << 16) | (unsigned int)src[e];
            lrank = atomicAdd(&hist[r], 1);       // LDS atomic: in-block rank
        }
        __syncthreads();
        for (int i = t; i < NR; i += 1024)
            base[i] = atomicAdd(&cursor[i], hist[i]);   // 125 global atomics
        __syncthreads();
        if (e < N_EDGES) {
            const int pos = base[r] + lrank;
            if (pos < RANGE_CAP)                  // statistically impossible
                area[r * RANGE_CAP + pos] = w;
        }
        return;
    }
    // ---- norm half: 32-lane group per node, 32 nodes per 1024-thr block ----
    const int nb  = b - A_BLOCKS;
    const int g   = threadIdx.x >> 5;
    const int sub = threadIdx.x & 31;
    const int node = nb * 32 + g;
    if (node >= N_NODES) return;
    float4 v = reinterpret_cast<const float4*>(feat + (size_t)node * D_FEAT)[sub];
    unsigned int w0 = (f2bf(v.y) << 16) | f2bf(v.x);
    unsigned int w1 = (f2bf(v.w) << 16) | f2bf(v.z);
    *reinterpret_cast<uint2*>(feat_bf + (size_t)node * 64 + sub * 2) =
        make_uint2(w0, w1);
    float s = v.x * v.x + v.y * v.y + v.z * v.z + v.w * v.w;
    #pragma unroll
    for (int off = 16; off > 0; off >>= 1)        // stays within 32-lane group
        s += __shfl_xor(s, off, 64);
    if (sub == 0) {
        inv_norm[node] = 1.0f / fmaxf(sqrtf(s), EPS);
    }
}

// ---------------------------------------------------------------------------
// K2 (pass B): per-range slot assignment with LDS atomics (no global RMW).
// One block per range; writes bucket[node*CAP + slot] and counts[node].
// ---------------------------------------------------------------------------
__global__ __launch_bounds__(256) void rank_kernel(
        const int* __restrict__ cursor,
        const unsigned int* __restrict__ area,
        int* __restrict__ counts,
        unsigned short* __restrict__ bucket) {
    __shared__ int hist[RANGE_NODES];
    const int r = blockIdx.x, t = threadIdx.x;
    for (int i = t; i < RANGE_NODES; i += 256) hist[i] = 0;
    __syncthreads();
    const int nE = min(cursor[r], RANGE_CAP);
    const unsigned int* ra = area + r * RANGE_CAP;
    for (int i = t; i < nE; i += 256) {
        const unsigned int w = ra[i];
        const int dl = (int)(w >> 16);
        const int slot = atomicAdd(&hist[dl], 1);         // LDS atomic
        if (slot < CAP)
            bucket[(size_t)(r * RANGE_NODES + dl) * CAP + slot] =
                (unsigned short)(w & 0xFFFFu);
    }
    __syncthreads();
    for (int i = t; i < RANGE_NODES; i += 256)
        counts[r * RANGE_NODES + i] = hist[i];
}

// ---------------------------------------------------------------------------
// K3: fused per-node weight + aggregation over bf16 rows (round-15 form).
// ---------------------------------------------------------------------------
__global__ void fused_agg(const unsigned int* __restrict__ feat_bf,
                          const float* __restrict__ inv_norm,
                          const int* __restrict__ counts,
                          const unsigned short* __restrict__ bucket,
                          const float* __restrict__ beta,
                          float* __restrict__ out) {
    const int lane = threadIdx.x & 63;
    const int grp  = lane >> 4;       // 0..3  : edge slot
    const int sub  = lane & 15;       // lane within group
    const int node = blockIdx.x * (blockDim.x >> 6) + (threadIdx.x >> 6);
    if (node >= N_NODES) return;

    const int cnt = min(counts[node], CAP);
    float4* orow = reinterpret_cast<float4*>(out + (size_t)node * D_FEAT);
    if (cnt == 0) {                   // degree-0: zero row (ref semantics)
        if (grp == 0) {
            orow[2 * sub] = make_float4(0.f, 0.f, 0.f, 0.f);
            orow[2 * sub + 1] = make_float4(0.f, 0.f, 0.f, 0.f);
        }
        return;
    }

    uint4 qd = reinterpret_cast<const uint4*>(feat_bf + (size_t)node * 64)[sub];
    const float bscale = inv_norm[node] * beta[0];

    float acc[8] = {0, 0, 0, 0, 0, 0, 0, 0};
    float denom = 0.0f;

    const int myid = (int)bucket[node * CAP + min(lane, cnt - 1)];

    const int s0 = __shfl(myid, min(grp, cnt - 1), 64);
    uint4 q0 = reinterpret_cast<const uint4*>(feat_bf + (size_t)s0 * 64)[sub];
    float in0 = inv_norm[s0];

    uint4 q1 = make_uint4(0u, 0u, 0u, 0u);
    float in1 = 0.0f;
    if (4 < cnt) {
        const int s1 = __shfl(myid, min(4 + grp, cnt - 1), 64);
        q1 = reinterpret_cast<const uint4*>(feat_bf + (size_t)s1 * 64)[sub];
        in1 = inv_norm[s1];
    }

    for (int k0 = 0; k0 < cnt; k0 += 4) {
        uint4 q2 = make_uint4(0u, 0u, 0u, 0u);
        float in2 = 0.0f;
        if (k0 + 8 < cnt) {                       // wave-uniform branch
            const int s2 = __shfl(myid, min(k0 + 8 + grp, cnt - 1), 64);
            q2 = reinterpret_cast<const uint4*>(feat_bf + (size_t)s2 * 64)[sub];
            in2 = inv_norm[s2];
        }

        float dot = dot2_bf16(q0.x, qd.x, 0.0f);
        dot = dot2_bf16(q0.y, qd.y, dot);
        dot = dot2_bf16(q0.z, qd.z, dot);
        dot = dot2_bf16(q0.w, qd.w, dot);
        #pragma unroll
        for (int off = 8; off > 0; off >>= 1)
            dot += __shfl_xor(dot, off, 64);

        const bool valid = (k0 + grp) < cnt;
        const float ee = valid ? __expf(dot * (bscale * in0)) : 0.0f;

        float a[8];
        a[0] = bf_lo(q0.x); a[1] = bf_hi(q0.x);
        a[2] = bf_lo(q0.y); a[3] = bf_hi(q0.y);
        a[4] = bf_lo(q0.z); a[5] = bf_hi(q0.z);
        a[6] = bf_lo(q0.w); a[7] = bf_hi(q0.w);
        #pragma unroll
        for (int j = 0; j < 8; ++j) acc[j] += ee * a[j];
        denom += ee;

        q0 = q1; in0 = in1;
        q1 = q2; in1 = in2;
    }

    #pragma unroll
    for (int j = 0; j < 8; ++j) {
        acc[j] += __shfl_xor(acc[j], 16, 64);
        acc[j] += __shfl_xor(acc[j], 32, 64);
    }
    denom += __shfl_xor(denom, 16, 64);
    denom += __shfl_xor(denom, 32, 64);

    if (grp == 0) {
        const float scale = 1.0f / denom;
        orow[2 * sub] = make_float4(acc[0] * scale, acc[1] * scale,
                                    acc[2] * scale, acc[3] * scale);
        orow[2 * sub + 1] = make_float4(acc[4] * scale, acc[5] * scale,
                                        acc[6] * scale, acc[7] * scale);
    }
}

extern "C" void kernel_launch(void* const* d_in, const int* in_sizes, int n_in,
                              void* d_out, int out_size, void* d_ws, size_t ws_size,
                              hipStream_t stream) {
    const float* feat = (const float*)d_in[0];
    const float* beta = (const float*)d_in[1];
    const int*   src  = (const int*)d_in[2];
    const int*   dst  = (const int*)d_in[3];
    float* out = (float*)d_out;

    // ws layout: inv_norm[N] f32 | counts[N] i32 | cursor[128] i32 |
    //            area[NR*RANGE_CAP] u32 (4MB) | bucket[N*CAP] u16 (6.4MB) |
    //            feat_bf[N*64] u32 (12.8MB)    total ~23.8 MB
    float*          inv_norm = (float*)d_ws;
    int*            counts   = (int*)(inv_norm + N_NODES);
    int*            cursor   = counts + N_NODES;
    unsigned int*   area     = (unsigned int*)(cursor + 128);
    unsigned short* bucket   = (unsigned short*)(area + (size_t)NR * RANGE_CAP);
    unsigned int*   feat_bf  = (unsigned int*)(bucket + (size_t)N_NODES * CAP);

    zero_cursor_kernel<<<1, 128, 0, stream>>>(cursor);
    partition_norm_kernel<<<A_BLOCKS + ANORM_BLOCKS, 1024, 0, stream>>>(
        src, dst, cursor, area, feat, inv_norm, feat_bf);
    rank_kernel<<<NR, 256, 0, stream>>>(cursor, area, counts, bucket);
    {
        const int WPB = 4;
        int blocks = (N_NODES + WPB - 1) / WPB;
        fused_agg<<<blocks, WPB * 64, 0, stream>>>(feat_bf, inv_norm, counts,
                                                   bucket, beta, out);
    }
}